// Round 8
// baseline (172.081 us; speedup 1.0000x reference)
//
#include <hip/hip_runtime.h>
#include <stdint.h>

#define N_NODES 100000
#define N_EDGES 600000
#define FEAT 128
#define BLK_M 128

typedef __attribute__((ext_vector_type(8))) short short8;
typedef __attribute__((ext_vector_type(4))) short sv4;
typedef __attribute__((ext_vector_type(4))) float floatx4;

typedef __attribute__((address_space(1))) const void gas_void;
typedef __attribute__((address_space(3))) void las_void;

__device__ __forceinline__ short f2bf(float f) {
    unsigned u = __builtin_bit_cast(unsigned, f);
    u = (u + 0x7FFFu + ((u >> 16) & 1u)) >> 16;   // RNE to bf16
    return (short)u;
}
__device__ __forceinline__ float bf2f(short s) {
    unsigned u = ((unsigned)(unsigned short)s) << 16;
    return __builtin_bit_cast(float, u);
}

// Wbt [n=256][k=128] bf16, Wbt[n][k] = concat(W1_top,W1_bot) column n (k-contiguous)
__global__ void cvt_w_kernel(const float* __restrict__ w1, short* __restrict__ wbt) {
    int i = blockIdx.x * 256 + threadIdx.x;   // 32768 = 256*128
    int n = i >> 7, k = i & 127;
    float f = (n < FEAT) ? w1[k * FEAT + n] : w1[(FEAT + k) * FEAT + (n - FEAT)];
    wbt[i] = f2bf(f);
}

// Y[100000][256] bf16 = X[100000][128] @ [W1t | W1b], b1 folded into cols 0..127.
// R8: latency/MLP fix. (a) W staged via fire-and-forget global_load_lds (16B), no
// VGPR round-trip; (b) X issued as float4 pairs BEFORE the barrier so its HBM latency
// hides under staging; 16 VMEM ops in flight per thread at block start.
// MFMA operand-swapped (R7-verified): D = W(A) * X^T(B) -> 8B vector Y-stores.
__global__ __launch_bounds__(512, 4) void node_gemm_kernel(
    const float* __restrict__ x, const short* __restrict__ wbt,
    const float* __restrict__ b1, short* __restrict__ y)
{
    __shared__ short lds_b[16 * 256 * 8];   // chunk-major [c=k/8][n], 64 KB

    const int tid  = threadIdx.x;
    const int lane = tid & 63;
    const int wave = tid >> 6;           // 0..7
    const int nl   = lane & 15;
    const int q    = lane >> 4;
    const int m0   = blockIdx.x * BLK_M + wave * 16;

    // (a) stage W: 8 x 16B global->LDS direct, per-lane source, linear LDS dest
#pragma unroll
    for (int it = 0; it < 8; ++it) {
        int j = it * 512 + tid;          // j = c*256 + n, c = j>>8, n = j&255
        int n = j & 255, c = j >> 8;
        const short* src = wbt + n * 128 + c * 8;
        short* dst = lds_b + j * 8;      // == ((c<<8)+n)*8 : lane-consecutive 16B
        __builtin_amdgcn_global_load_lds((gas_void*)(const void*)src,
                                         (las_void*)(void*)dst, 16, 0, 0);
    }

    // (b) X loads issued now -> overlap staging + barrier drain
    const int node = m0 + nl;
    const int nsrc = (node < N_NODES) ? node : 0;
    floatx4 xv[8];
#pragma unroll
    for (int s = 0; s < 4; ++s) {
        const float* p = x + (size_t)nsrc * FEAT + s * 32 + q * 8;
        xv[2 * s]     = *(const floatx4*)(p);
        xv[2 * s + 1] = *(const floatx4*)(p + 4);
    }

    __syncthreads();   // drains vmcnt -> LDS valid, X in registers

    // convert X to bf16 B-fragments: a[s][j] = X[node][32s + 8q + j]
    short8 a[4];
#pragma unroll
    for (int s = 0; s < 4; ++s) {
        short8 av;
#pragma unroll
        for (int j = 0; j < 8; ++j) av[j] = f2bf(xv[2 * s + (j >> 2)][j & 3]);
        a[s] = av;
    }

    floatx4 acc[16];
#pragma unroll
    for (int nt = 0; nt < 16; ++nt) acc[nt] = (floatx4)(0.0f);

#pragma unroll
    for (int s = 0; s < 4; ++s) {
        const int crow = (s * 4 + q) << 8;   // chunk c = s*4+q, row base c*256
#pragma unroll
        for (int nt = 0; nt < 16; ++nt) {
            // A = W rows [n = nt*16+nl][k = 32s+8q+j]
            short8 wf = *(const short8*)(lds_b + ((crow + nt * 16 + nl) << 3));
            // D[row = n_local = q*4+r][col = m_local = nl]
            acc[nt] = __builtin_amdgcn_mfma_f32_16x16x32_bf16(wf, a[s], acc[nt], 0, 0, 0);
        }
    }

    // Epilogue: lane owns node = m0+nl, n = nt*16 + q*4 + r -> 8B vector stores
    if (node < N_NODES) {
        short* yr = y + (size_t)node * 256 + q * 4;
#pragma unroll
        for (int nt = 0; nt < 8; ++nt) {     // u-half: fold b1
            floatx4 bb = *(const floatx4*)(b1 + nt * 16 + q * 4);
            sv4 o;
            o[0] = f2bf(acc[nt][0] + bb[0]); o[1] = f2bf(acc[nt][1] + bb[1]);
            o[2] = f2bf(acc[nt][2] + bb[2]); o[3] = f2bf(acc[nt][3] + bb[3]);
            *(sv4*)(yr + nt * 16) = o;
        }
#pragma unroll
        for (int nt = 8; nt < 16; ++nt) {    // v-half
            sv4 o;
            o[0] = f2bf(acc[nt][0]); o[1] = f2bf(acc[nt][1]);
            o[2] = f2bf(acc[nt][2]); o[3] = f2bf(acc[nt][3]);
            *(sv4*)(yr + nt * 16) = o;
        }
    }
}

// Per-edge: out = sigmoid(relu(Yu[r] + Yv[c]) . W2 + b2)   (b1 pre-folded into Yu)
// Batch-4 consecutive edges, no register double-buffering. (Verified round 6: 44.6us)
__global__ __launch_bounds__(256) void edge_kernel(
    const short* __restrict__ y, const int* __restrict__ eidx,
    const float* __restrict__ w2, const float* __restrict__ b2,
    float* __restrict__ out)
{
    const int l = threadIdx.x & 15;

    float w2r[8];
#pragma unroll
    for (int j = 0; j < 8; ++j) w2r[j] = w2[l * 8 + j];
    const float bias2 = b2[0];

    const int slot   = blockIdx.x * 16 + (threadIdx.x >> 4);
    const int nslots = gridDim.x * 16;               // 32768

    for (int eb = slot * 4; eb < N_EDGES; eb += nslots * 4) {
        int4 rr = *(const int4*)(eidx + eb);
        int4 cc = *(const int4*)(eidx + N_EDGES + eb);

        short8 u0 = *(const short8*)(y + (size_t)rr.x * 256 + l * 8);
        short8 u1 = *(const short8*)(y + (size_t)rr.y * 256 + l * 8);
        short8 u2 = *(const short8*)(y + (size_t)rr.z * 256 + l * 8);
        short8 u3 = *(const short8*)(y + (size_t)rr.w * 256 + l * 8);
        short8 v0 = *(const short8*)(y + (size_t)cc.x * 256 + 128 + l * 8);
        short8 v1 = *(const short8*)(y + (size_t)cc.y * 256 + 128 + l * 8);
        short8 v2 = *(const short8*)(y + (size_t)cc.z * 256 + 128 + l * 8);
        short8 v3 = *(const short8*)(y + (size_t)cc.w * 256 + 128 + l * 8);

        float p0 = 0.0f, p1 = 0.0f, p2 = 0.0f, p3 = 0.0f;
#pragma unroll
        for (int j = 0; j < 8; ++j) {
            p0 = fmaf(fmaxf(bf2f(u0[j]) + bf2f(v0[j]), 0.0f), w2r[j], p0);
            p1 = fmaf(fmaxf(bf2f(u1[j]) + bf2f(v1[j]), 0.0f), w2r[j], p1);
            p2 = fmaf(fmaxf(bf2f(u2[j]) + bf2f(v2[j]), 0.0f), w2r[j], p2);
            p3 = fmaf(fmaxf(bf2f(u3[j]) + bf2f(v3[j]), 0.0f), w2r[j], p3);
        }
#pragma unroll
        for (int d = 1; d < 16; d <<= 1) {
            p0 += __shfl_xor(p0, d);
            p1 += __shfl_xor(p1, d);
            p2 += __shfl_xor(p2, d);
            p3 += __shfl_xor(p3, d);
        }

        if (l == 0) {
            floatx4 o;
            o[0] = 1.0f / (1.0f + __expf(-(p0 + bias2)));
            o[1] = 1.0f / (1.0f + __expf(-(p1 + bias2)));
            o[2] = 1.0f / (1.0f + __expf(-(p2 + bias2)));
            o[3] = 1.0f / (1.0f + __expf(-(p3 + bias2)));
            *(floatx4*)(out + eb) = o;
        }
    }
}

extern "C" void kernel_launch(void* const* d_in, const int* in_sizes, int n_in,
                              void* d_out, int out_size, void* d_ws, size_t ws_size,
                              hipStream_t stream) {
    const float* x  = (const float*)d_in[0];
    const int*   ei = (const int*)d_in[1];
    const float* W1 = (const float*)d_in[2];
    const float* b1 = (const float*)d_in[3];
    const float* W2 = (const float*)d_in[4];
    const float* b2 = (const float*)d_in[5];
    float* out = (float*)d_out;

    short* ybf = (short*)d_ws;                          // 100000*256 shorts = 51.2 MB
    short* wbt = ybf + (size_t)N_NODES * 256;           // 32768 shorts

    cvt_w_kernel<<<32768 / 256, 256, 0, stream>>>(W1, wbt);

    int mblocks = (N_NODES + BLK_M - 1) / BLK_M;        // 782
    node_gemm_kernel<<<mblocks, 512, 0, stream>>>(x, wbt, b1, ybf);

    edge_kernel<<<2048, 256, 0, stream>>>(ybf, ei, W2, b2, out);
}

// Round 9
// 160.608 us; speedup vs baseline: 1.0714x; 1.0714x over previous
//
#include <hip/hip_runtime.h>
#include <stdint.h>

#define N_NODES 100000
#define N_EDGES 600000
#define FEAT 128
#define BLK_M 128

typedef __attribute__((ext_vector_type(8))) short short8;
typedef __attribute__((ext_vector_type(4))) short sv4;
typedef __attribute__((ext_vector_type(4))) float floatx4;

__device__ __forceinline__ short f2bf(float f) {
    unsigned u = __builtin_bit_cast(unsigned, f);
    u = (u + 0x7FFFu + ((u >> 16) & 1u)) >> 16;   // RNE to bf16
    return (short)u;
}
__device__ __forceinline__ float bf2f(short s) {
    unsigned u = ((unsigned)(unsigned short)s) << 16;
    return __builtin_bit_cast(float, u);
}

// Y[100000][256] bf16 = X[100000][128] @ [W1t | W1b], b1 folded into cols 0..127.
// R9: W-conversion FUSED into the GEMM prologue (3 dispatches -> 2). Each block
// converts W1 fp32 -> bf16 chunk-major LDS directly (W1 = 128KB, L2-hot; redundant
// per-block conversion is ~1.5K cycles/CU wave-level). No wbt workspace round-trip.
// MFMA operand-swapped (R7-verified): D = W(A) * X^T(B) -> 8B vector Y-stores.
__global__ __launch_bounds__(512, 4) void node_gemm_kernel(
    const float* __restrict__ x, const float* __restrict__ w1,
    const float* __restrict__ b1, short* __restrict__ y)
{
    __shared__ short lds_b[16 * 256 * 8];   // chunk-major [c=k/8][n], 64 KB

    const int tid  = threadIdx.x;
    const int lane = tid & 63;
    const int wave = tid >> 6;           // 0..7
    const int nl   = lane & 15;
    const int q    = lane >> 4;
    const int m0   = blockIdx.x * BLK_M + wave * 16;

    // X loads issued first: HBM latency overlaps the W conversion below
    const int node = m0 + nl;
    const int nsrc = (node < N_NODES) ? node : 0;
    floatx4 xv[8];
#pragma unroll
    for (int s = 0; s < 4; ++s) {
        const float* p = x + (size_t)nsrc * FEAT + s * 32 + q * 8;
        xv[2 * s]     = *(const floatx4*)(p);
        xv[2 * s + 1] = *(const floatx4*)(p + 4);
    }

    // Convert W1 -> lds_b: element (c*256+n)*8 + j == Wbt[n][c*8+j]
    //   = (n<128) ? W1[c*8+j][n] : W1[128+c*8+j][n-128]      (W1 row-major [256][128])
#pragma unroll
    for (int it = 0; it < 8; ++it) {
        int t = it * 512 + tid;          // 4096 (c,n) groups
        int n = t & 255, c = t >> 8;
        const float* src = (n < 128) ? (w1 + (c * 8) * 128 + n)
                                     : (w1 + (128 + c * 8) * 128 + (n - 128));
        short8 v;
#pragma unroll
        for (int j = 0; j < 8; ++j) v[j] = f2bf(src[j * 128]);
        *(short8*)(lds_b + t * 8) = v;   // lane-consecutive 16B, conflict-free
    }

    __syncthreads();

    // convert X to bf16 B-fragments: a[s][j] = X[node][32s + 8q + j]
    short8 a[4];
#pragma unroll
    for (int s = 0; s < 4; ++s) {
        short8 av;
#pragma unroll
        for (int j = 0; j < 8; ++j) av[j] = f2bf(xv[2 * s + (j >> 2)][j & 3]);
        a[s] = av;
    }

    floatx4 acc[16];
#pragma unroll
    for (int nt = 0; nt < 16; ++nt) acc[nt] = (floatx4)(0.0f);

#pragma unroll
    for (int s = 0; s < 4; ++s) {
        const int crow = (s * 4 + q) << 8;   // chunk c = s*4+q, row base c*256
#pragma unroll
        for (int nt = 0; nt < 16; ++nt) {
            // A = W rows [n = nt*16+nl][k = 32s+8q+j]
            short8 wf = *(const short8*)(lds_b + ((crow + nt * 16 + nl) << 3));
            // D[row = n_local = q*4+r][col = m_local = nl]
            acc[nt] = __builtin_amdgcn_mfma_f32_16x16x32_bf16(wf, a[s], acc[nt], 0, 0, 0);
        }
    }

    // Epilogue: lane owns node = m0+nl, n = nt*16 + q*4 + r -> 8B vector stores
    if (node < N_NODES) {
        short* yr = y + (size_t)node * 256 + q * 4;
#pragma unroll
        for (int nt = 0; nt < 8; ++nt) {     // u-half: fold b1
            floatx4 bb = *(const floatx4*)(b1 + nt * 16 + q * 4);
            sv4 o;
            o[0] = f2bf(acc[nt][0] + bb[0]); o[1] = f2bf(acc[nt][1] + bb[1]);
            o[2] = f2bf(acc[nt][2] + bb[2]); o[3] = f2bf(acc[nt][3] + bb[3]);
            *(sv4*)(yr + nt * 16) = o;
        }
#pragma unroll
        for (int nt = 8; nt < 16; ++nt) {    // v-half
            sv4 o;
            o[0] = f2bf(acc[nt][0]); o[1] = f2bf(acc[nt][1]);
            o[2] = f2bf(acc[nt][2]); o[3] = f2bf(acc[nt][3]);
            *(sv4*)(yr + nt * 16) = o;
        }
    }
}

// Per-edge: out = sigmoid(relu(Yu[r] + Yv[c]) . W2 + b2)   (b1 pre-folded into Yu)
// Batch-4 consecutive edges, no register double-buffering. (Verified round 6: 44.6us)
__global__ __launch_bounds__(256) void edge_kernel(
    const short* __restrict__ y, const int* __restrict__ eidx,
    const float* __restrict__ w2, const float* __restrict__ b2,
    float* __restrict__ out)
{
    const int l = threadIdx.x & 15;

    float w2r[8];
#pragma unroll
    for (int j = 0; j < 8; ++j) w2r[j] = w2[l * 8 + j];
    const float bias2 = b2[0];

    const int slot   = blockIdx.x * 16 + (threadIdx.x >> 4);
    const int nslots = gridDim.x * 16;               // 32768

    for (int eb = slot * 4; eb < N_EDGES; eb += nslots * 4) {
        int4 rr = *(const int4*)(eidx + eb);
        int4 cc = *(const int4*)(eidx + N_EDGES + eb);

        short8 u0 = *(const short8*)(y + (size_t)rr.x * 256 + l * 8);
        short8 u1 = *(const short8*)(y + (size_t)rr.y * 256 + l * 8);
        short8 u2 = *(const short8*)(y + (size_t)rr.z * 256 + l * 8);
        short8 u3 = *(const short8*)(y + (size_t)rr.w * 256 + l * 8);
        short8 v0 = *(const short8*)(y + (size_t)cc.x * 256 + 128 + l * 8);
        short8 v1 = *(const short8*)(y + (size_t)cc.y * 256 + 128 + l * 8);
        short8 v2 = *(const short8*)(y + (size_t)cc.z * 256 + 128 + l * 8);
        short8 v3 = *(const short8*)(y + (size_t)cc.w * 256 + 128 + l * 8);

        float p0 = 0.0f, p1 = 0.0f, p2 = 0.0f, p3 = 0.0f;
#pragma unroll
        for (int j = 0; j < 8; ++j) {
            p0 = fmaf(fmaxf(bf2f(u0[j]) + bf2f(v0[j]), 0.0f), w2r[j], p0);
            p1 = fmaf(fmaxf(bf2f(u1[j]) + bf2f(v1[j]), 0.0f), w2r[j], p1);
            p2 = fmaf(fmaxf(bf2f(u2[j]) + bf2f(v2[j]), 0.0f), w2r[j], p2);
            p3 = fmaf(fmaxf(bf2f(u3[j]) + bf2f(v3[j]), 0.0f), w2r[j], p3);
        }
#pragma unroll
        for (int d = 1; d < 16; d <<= 1) {
            p0 += __shfl_xor(p0, d);
            p1 += __shfl_xor(p1, d);
            p2 += __shfl_xor(p2, d);
            p3 += __shfl_xor(p3, d);
        }

        if (l == 0) {
            floatx4 o;
            o[0] = 1.0f / (1.0f + __expf(-(p0 + bias2)));
            o[1] = 1.0f / (1.0f + __expf(-(p1 + bias2)));
            o[2] = 1.0f / (1.0f + __expf(-(p2 + bias2)));
            o[3] = 1.0f / (1.0f + __expf(-(p3 + bias2)));
            *(floatx4*)(out + eb) = o;
        }
    }
}

extern "C" void kernel_launch(void* const* d_in, const int* in_sizes, int n_in,
                              void* d_out, int out_size, void* d_ws, size_t ws_size,
                              hipStream_t stream) {
    const float* x  = (const float*)d_in[0];
    const int*   ei = (const int*)d_in[1];
    const float* W1 = (const float*)d_in[2];
    const float* b1 = (const float*)d_in[3];
    const float* W2 = (const float*)d_in[4];
    const float* b2 = (const float*)d_in[5];
    float* out = (float*)d_out;

    short* ybf = (short*)d_ws;                          // 100000*256 shorts = 51.2 MB

    int mblocks = (N_NODES + BLK_M - 1) / BLK_M;        // 782
    node_gemm_kernel<<<mblocks, 512, 0, stream>>>(x, W1, b1, ybf);

    edge_kernel<<<2048, 256, 0, stream>>>(ybf, ei, W2, b2, out);
}

// Round 10
// 156.223 us; speedup vs baseline: 1.1015x; 1.0281x over previous
//
#include <hip/hip_runtime.h>
#include <stdint.h>

#define N_NODES 100000
#define N_EDGES 600000
#define FEAT 128
#define BLK_M 128

typedef __attribute__((ext_vector_type(8))) short short8;
typedef __attribute__((ext_vector_type(4))) short sv4;
typedef __attribute__((ext_vector_type(4))) float floatx4;

__device__ __forceinline__ short f2bf(float f) {
    unsigned u = __builtin_bit_cast(unsigned, f);
    u = (u + 0x7FFFu + ((u >> 16) & 1u)) >> 16;   // RNE to bf16
    return (short)u;
}
__device__ __forceinline__ float bf2f(short s) {
    unsigned u = ((unsigned)(unsigned short)s) << 16;
    return __builtin_bit_cast(float, u);
}

// Y[100000][256] bf16 = X[100000][128] @ [W1t | W1b], b1 folded into cols 0..127.
// (byte-identical to R9 — verified, <44.4us; W conversion fused into prologue)
__global__ __launch_bounds__(512, 4) void node_gemm_kernel(
    const float* __restrict__ x, const float* __restrict__ w1,
    const float* __restrict__ b1, short* __restrict__ y)
{
    __shared__ short lds_b[16 * 256 * 8];   // chunk-major [c=k/8][n], 64 KB

    const int tid  = threadIdx.x;
    const int lane = tid & 63;
    const int wave = tid >> 6;           // 0..7
    const int nl   = lane & 15;
    const int q    = lane >> 4;
    const int m0   = blockIdx.x * BLK_M + wave * 16;

    // X loads issued first: HBM latency overlaps the W conversion below
    const int node = m0 + nl;
    const int nsrc = (node < N_NODES) ? node : 0;
    floatx4 xv[8];
#pragma unroll
    for (int s = 0; s < 4; ++s) {
        const float* p = x + (size_t)nsrc * FEAT + s * 32 + q * 8;
        xv[2 * s]     = *(const floatx4*)(p);
        xv[2 * s + 1] = *(const floatx4*)(p + 4);
    }

    // Convert W1 -> lds_b: element (c*256+n)*8 + j == Wbt[n][c*8+j]
#pragma unroll
    for (int it = 0; it < 8; ++it) {
        int t = it * 512 + tid;          // 4096 (c,n) groups
        int n = t & 255, c = t >> 8;
        const float* src = (n < 128) ? (w1 + (c * 8) * 128 + n)
                                     : (w1 + (128 + c * 8) * 128 + (n - 128));
        short8 v;
#pragma unroll
        for (int j = 0; j < 8; ++j) v[j] = f2bf(src[j * 128]);
        *(short8*)(lds_b + t * 8) = v;   // lane-consecutive 16B, conflict-free
    }

    __syncthreads();

    // convert X to bf16 B-fragments: a[s][j] = X[node][32s + 8q + j]
    short8 a[4];
#pragma unroll
    for (int s = 0; s < 4; ++s) {
        short8 av;
#pragma unroll
        for (int j = 0; j < 8; ++j) av[j] = f2bf(xv[2 * s + (j >> 2)][j & 3]);
        a[s] = av;
    }

    floatx4 acc[16];
#pragma unroll
    for (int nt = 0; nt < 16; ++nt) acc[nt] = (floatx4)(0.0f);

#pragma unroll
    for (int s = 0; s < 4; ++s) {
        const int crow = (s * 4 + q) << 8;   // chunk c = s*4+q, row base c*256
#pragma unroll
        for (int nt = 0; nt < 16; ++nt) {
            short8 wf = *(const short8*)(lds_b + ((crow + nt * 16 + nl) << 3));
            // D[row = n_local = q*4+r][col = m_local = nl]
            acc[nt] = __builtin_amdgcn_mfma_f32_16x16x32_bf16(wf, a[s], acc[nt], 0, 0, 0);
        }
    }

    // Epilogue: lane owns node = m0+nl, n = nt*16 + q*4 + r -> 8B vector stores
    if (node < N_NODES) {
        short* yr = y + (size_t)node * 256 + q * 4;
#pragma unroll
        for (int nt = 0; nt < 8; ++nt) {     // u-half: fold b1
            floatx4 bb = *(const floatx4*)(b1 + nt * 16 + q * 4);
            sv4 o;
            o[0] = f2bf(acc[nt][0] + bb[0]); o[1] = f2bf(acc[nt][1] + bb[1]);
            o[2] = f2bf(acc[nt][2] + bb[2]); o[3] = f2bf(acc[nt][3] + bb[3]);
            *(sv4*)(yr + nt * 16) = o;
        }
#pragma unroll
        for (int nt = 8; nt < 16; ++nt) {    // v-half
            sv4 o;
            o[0] = f2bf(acc[nt][0]); o[1] = f2bf(acc[nt][1]);
            o[2] = f2bf(acc[nt][2]); o[3] = f2bf(acc[nt][3]);
            *(sv4*)(yr + nt * 16) = o;
        }
    }
}

// Per-edge: out = sigmoid(relu(Yu[r] + Yv[c]) . W2 + b2)   (b1 pre-folded into Yu)
// R10: batch-8 edges per slot -> 16 independent gathers in flight (2x MLP of R6's
// batch-4). N_EDGES % 8 == 0, so every batch is full (no per-edge guards).
__global__ __launch_bounds__(256, 4) void edge_kernel(
    const short* __restrict__ y, const int* __restrict__ eidx,
    const float* __restrict__ w2, const float* __restrict__ b2,
    float* __restrict__ out)
{
    const int l = threadIdx.x & 15;

    float w2r[8];
#pragma unroll
    for (int j = 0; j < 8; ++j) w2r[j] = w2[l * 8 + j];
    const float bias2 = b2[0];

    const int slot   = blockIdx.x * 16 + (threadIdx.x >> 4);
    const int nslots = gridDim.x * 16;               // 32768

    for (int eb = slot * 8; eb < N_EDGES; eb += nslots * 8) {
        int4 r0 = *(const int4*)(eidx + eb);
        int4 r1 = *(const int4*)(eidx + eb + 4);
        int4 c0 = *(const int4*)(eidx + N_EDGES + eb);
        int4 c1 = *(const int4*)(eidx + N_EDGES + eb + 4);

        short8 u[8], v[8];
        u[0] = *(const short8*)(y + (size_t)r0.x * 256 + l * 8);
        u[1] = *(const short8*)(y + (size_t)r0.y * 256 + l * 8);
        u[2] = *(const short8*)(y + (size_t)r0.z * 256 + l * 8);
        u[3] = *(const short8*)(y + (size_t)r0.w * 256 + l * 8);
        u[4] = *(const short8*)(y + (size_t)r1.x * 256 + l * 8);
        u[5] = *(const short8*)(y + (size_t)r1.y * 256 + l * 8);
        u[6] = *(const short8*)(y + (size_t)r1.z * 256 + l * 8);
        u[7] = *(const short8*)(y + (size_t)r1.w * 256 + l * 8);
        v[0] = *(const short8*)(y + (size_t)c0.x * 256 + 128 + l * 8);
        v[1] = *(const short8*)(y + (size_t)c0.y * 256 + 128 + l * 8);
        v[2] = *(const short8*)(y + (size_t)c0.z * 256 + 128 + l * 8);
        v[3] = *(const short8*)(y + (size_t)c0.w * 256 + 128 + l * 8);
        v[4] = *(const short8*)(y + (size_t)c1.x * 256 + 128 + l * 8);
        v[5] = *(const short8*)(y + (size_t)c1.y * 256 + 128 + l * 8);
        v[6] = *(const short8*)(y + (size_t)c1.z * 256 + 128 + l * 8);
        v[7] = *(const short8*)(y + (size_t)c1.w * 256 + 128 + l * 8);

        float p[8];
#pragma unroll
        for (int b = 0; b < 8; ++b) {
            float acc = 0.0f;
#pragma unroll
            for (int j = 0; j < 8; ++j) {
                float h = bf2f(u[b][j]) + bf2f(v[b][j]);
                acc = fmaf(fmaxf(h, 0.0f), w2r[j], acc);
            }
            p[b] = acc;
        }
#pragma unroll
        for (int d = 1; d < 16; d <<= 1) {
#pragma unroll
            for (int b = 0; b < 8; ++b) p[b] += __shfl_xor(p[b], d);
        }

        if (l == 0) {
            floatx4 o0, o1;
            o0[0] = 1.0f / (1.0f + __expf(-(p[0] + bias2)));
            o0[1] = 1.0f / (1.0f + __expf(-(p[1] + bias2)));
            o0[2] = 1.0f / (1.0f + __expf(-(p[2] + bias2)));
            o0[3] = 1.0f / (1.0f + __expf(-(p[3] + bias2)));
            o1[0] = 1.0f / (1.0f + __expf(-(p[4] + bias2)));
            o1[1] = 1.0f / (1.0f + __expf(-(p[5] + bias2)));
            o1[2] = 1.0f / (1.0f + __expf(-(p[6] + bias2)));
            o1[3] = 1.0f / (1.0f + __expf(-(p[7] + bias2)));
            *(floatx4*)(out + eb)     = o0;
            *(floatx4*)(out + eb + 4) = o1;
        }
    }
}

extern "C" void kernel_launch(void* const* d_in, const int* in_sizes, int n_in,
                              void* d_out, int out_size, void* d_ws, size_t ws_size,
                              hipStream_t stream) {
    const float* x  = (const float*)d_in[0];
    const int*   ei = (const int*)d_in[1];
    const float* W1 = (const float*)d_in[2];
    const float* b1 = (const float*)d_in[3];
    const float* W2 = (const float*)d_in[4];
    const float* b2 = (const float*)d_in[5];
    float* out = (float*)d_out;

    short* ybf = (short*)d_ws;                          // 100000*256 shorts = 51.2 MB

    int mblocks = (N_NODES + BLK_M - 1) / BLK_M;        // 782
    node_gemm_kernel<<<mblocks, 512, 0, stream>>>(x, W1, b1, ybf);

    edge_kernel<<<2048, 256, 0, stream>>>(ybf, ei, W2, b2, out);
}